// Round 1
// baseline (662.031 us; speedup 1.0000x reference)
//
#include <hip/hip_runtime.h>

// Palettized 3x3 VALID conv as implicit GEMM:
//   C[M=16*254*254, 64] = A[M, K=576] * B[K=576, 64],  K = (kh*3+kw)*64 + c
// Persistent-2 pipelined version: each block computes TWO oh-adjacent 4x64x64
// output tiles. K-loop split by channel half (cblk 0-3 = c0..31, cblk 4-7 =
// c32..63). While computing one half from LDS, the next half-stage's global
// loads are software-pipelined (reg-staged, depth-4) inside the MFMA loop.
// Barriers are raw s_barrier + lgkmcnt(0) only (no vmcnt drain).

typedef __bf16 bf16x8 __attribute__((ext_vector_type(8)));
typedef float f32x4 __attribute__((ext_vector_type(4)));
typedef float f32x2 __attribute__((ext_vector_type(2)));

union Frag {
    uint4 q;
    bf16x8 v;
};

#define LGKM_BARRIER() do { \
    asm volatile("s_waitcnt lgkmcnt(0)" ::: "memory"); \
    __builtin_amdgcn_s_barrier(); \
    asm volatile("" ::: "memory"); } while (0)

// ---- B dequant/swizzle: Bws[s]  s = (kc*4 + nt)*64 + lane, 16B per slot.
// lane holds B[k = kc*32 + (lane>>4)*8 + j][o = nt*16 + (lane&15)], j=0..7
// with k = (kh*3+kw)*64 + c  ->  kc: r = kc>>1 fixed, c = (kc&1)*32 + (lane>>4)*8 + j.
__global__ __launch_bounds__(256) void dequant_B(
        const float* __restrict__ lut, const int* __restrict__ widx,
        uint4* __restrict__ Bws) {
    int s = blockIdx.x * 256 + threadIdx.x;   // 0..4607
    int l = s & 63;
    int nt = (s >> 6) & 3;
    int kc = s >> 8;
    if (kc >= 18) return;
    int r = kc >> 1;
    int kh = r / 3, kw = r - kh * 3;
    int o = nt * 16 + (l & 15);
    int c0 = (kc & 1) * 32 + (l >> 4) * 8;
    Frag f;
#pragma unroll
    for (int j = 0; j < 8; ++j) {
        int c = c0 + j;
        int idx = widx[((o * 64 + c) * 3 + kh) * 3 + kw];
        f.v[j] = (__bf16)lut[idx];
    }
    Bws[s] = f.q;
}

// LDS layout: ldsA[cblk][pix] as 16B granules; pix = row*66 + col (row 0..5, col 0..65)
// granule = 8 bf16 = channels cblk*8 .. cblk*8+7 of pixel (row,col).
#define LDS_PIX 396

__global__ __launch_bounds__(256, 3) void conv_mfma(
        const float* __restrict__ x, const float* __restrict__ bias,
        const uint4* __restrict__ Bws, float* __restrict__ out) {
    __shared__ uint4 ldsA[8 * LDS_PIX];   // 50688 B

    int bx = blockIdx.x;
    // XCD-chunked swizzle: 2048 blocks, 8 XCDs -> 256 contiguous tiles per XCD.
    int swz = (bx & 7) * 256 + (bx >> 3);
    int ow0 = (swz & 3) * 64;          // 0,64,128,192
    int ohp = (swz >> 2) & 31;         // oh-pair 0..31
    int n   = swz >> 7;                // 0..15
    int oh0a = ohp * 8;                // tile0 rows oh0a..oh0a+3
    int oh0b = oh0a + 4;               // tile1 rows

    int t = threadIdx.x;
    int w = t >> 6, l = t & 63;
    int l15 = l & 15, l4 = l >> 4;

    const float* xn = x + (size_t)n * (64 * 256 * 256);

    // tail-job constants (cols 64,65; handled by t<48: 4 cblk x 6 row x 2 col)
    int tl_cb  = t & 3;
    int tl_rc  = t >> 2;            // 0..11 for t<48
    int tl_rr  = tl_rc >> 1;
    int tl_col = 64 + (tl_rc & 1);
    int tl_xc  = ow0 + tl_col; if (tl_xc > 255) tl_xc = 255;

    f32x4 acc[4][4];

    // ---- plain (unpipelined) half-stage: wave w stages cblk = half*4+w, rows 0..5
    auto stage_plain = [&](int half, int oh0s) {
        const float* sb = xn + (half * 4 + w) * 524288 + ow0 + l;
#pragma unroll
        for (int j = 0; j < 6; ++j) {
            int y = oh0s + j; if (y > 255) y = 255;
            const float* src = sb + y * 256;
            Frag f;
#pragma unroll
            for (int jj = 0; jj < 8; ++jj)
                f.v[jj] = (__bf16)src[jj * 65536];
            ldsA[(half * 4 + w) * LDS_PIX + j * 66 + l] = f.q;
        }
        if (t < 48) {
            int y = oh0s + tl_rr; if (y > 255) y = 255;
            const float* src = xn + (half * 4 + tl_cb) * 524288 + y * 256 + tl_xc;
            Frag f;
#pragma unroll
            for (int jj = 0; jj < 8; ++jj)
                f.v[jj] = (__bf16)src[jj * 65536];
            ldsA[(half * 4 + tl_cb) * LDS_PIX + tl_rr * 66 + tl_col] = f.q;
        }
    };

    // ---- compute 9 kc of parity PAR, optionally pipelining the stage of
    // half `shalf` (rows of tile with origin oh0s). Jobs: 0..5 = (cblk=shalf*4+w,
    // row=j, cols 0..63); job 6 = tail (t<48). Issue job i at iter i, consume
    // job i-3 after iter i's MFMAs. Depth-4 static buffer (rule #20: all
    // indices compile-time after full unroll).
    auto region = [&](int PAR, bool STAGE, int shalf, int oh0s) {
        float pre[4][8];
        const float* sb = xn + (shalf * 4 + w) * 524288 + ow0 + l;
#pragma unroll
        for (int i = 0; i < 9; ++i) {
            // issue job i
            if (STAGE && i < 7) {
                if (i < 6) {
                    int y = oh0s + i; if (y > 255) y = 255;
                    const float* src = sb + y * 256;
#pragma unroll
                    for (int jj = 0; jj < 8; ++jj)
                        pre[i & 3][jj] = src[jj * 65536];
                } else if (t < 48) {
                    int y = oh0s + tl_rr; if (y > 255) y = 255;
                    const float* src = xn + (shalf * 4 + tl_cb) * 524288 + y * 256 + tl_xc;
#pragma unroll
                    for (int jj = 0; jj < 8; ++jj)
                        pre[6 & 3][jj] = src[jj * 65536];
                }
            }
            // compute kc = 2*i + PAR   (kh = i/3, kw = i%3 fold at compile time)
            {
                int kh = i / 3, kw = i - kh * 3;
                int cblk = PAR * 4 + l4;
                int pix = (w + kh) * 66 + l15 + kw;
                int kc = 2 * i + PAR;
                Frag b[4];
#pragma unroll
                for (int nt = 0; nt < 4; ++nt)
                    b[nt].q = Bws[(kc * 4 + nt) * 64 + l];
                Frag a[4];
#pragma unroll
                for (int mt = 0; mt < 4; ++mt)
                    a[mt].q = ldsA[cblk * LDS_PIX + pix + mt * 16];
#pragma unroll
                for (int mt = 0; mt < 4; ++mt)
#pragma unroll
                    for (int nt = 0; nt < 4; ++nt)
                        acc[mt][nt] = __builtin_amdgcn_mfma_f32_16x16x32_bf16(
                            a[mt].v, b[nt].v, acc[mt][nt], 0, 0, 0);
            }
            // consume job i-3 (cvt + ds_write) after this iter's MFMAs
            if (STAGE && i >= 3) {
                int jd = i - 3;                     // 0..5 (all main jobs)
                Frag f;
#pragma unroll
                for (int jj = 0; jj < 8; ++jj)
                    f.v[jj] = (__bf16)pre[jd & 3][jj];
                ldsA[(shalf * 4 + w) * LDS_PIX + jd * 66 + l] = f.q;
            }
        }
        // drain job 6 (tail)
        if (STAGE && t < 48) {
            Frag f;
#pragma unroll
            for (int jj = 0; jj < 8; ++jj)
                f.v[jj] = (__bf16)pre[6 & 3][jj];
            ldsA[(shalf * 4 + tl_cb) * LDS_PIX + tl_rr * 66 + tl_col] = f.q;
        }
    };

    // ---- epilogue: C/D layout col(o)=lane&15, row(ow_l)=(lane>>4)*4+reg.
    // acc[mt][nt][0..3] are 4 consecutive ow -> 2x f32x2 stores (addr 8B-aligned:
    // element offset mod 4 is {0,2} since 64516%4==0 and oh*254 is even).
    auto epilogue = [&](int oh0t) {
        int oh = oh0t + w;
        if (oh < 254) {
#pragma unroll
            for (int nt = 0; nt < 4; ++nt) {
                int o = nt * 16 + l15;
                float bv = bias[o];
                float* ob = out + (((size_t)n * 64 + o) * 254 + oh) * 254 + ow0;
#pragma unroll
                for (int mt = 0; mt < 4; ++mt) {
                    int owl = mt * 16 + l4 * 4;
                    f32x4 v;
#pragma unroll
                    for (int rg = 0; rg < 4; ++rg)
                        v[rg] = acc[mt][nt][rg] + bv;
                    if (ow0 + owl + 3 < 254) {
                        *(f32x2*)(ob + owl)     = f32x2{v[0], v[1]};
                        *(f32x2*)(ob + owl + 2) = f32x2{v[2], v[3]};
                    } else {
#pragma unroll
                        for (int rg = 0; rg < 4; ++rg)
                            if (ow0 + owl + rg < 254)
                                ob[owl + rg] = v[rg];
                    }
                }
            }
        }
    };

#pragma unroll
    for (int mt = 0; mt < 4; ++mt)
#pragma unroll
        for (int nt = 0; nt < 4; ++nt)
            acc[mt][nt] = f32x4{0.f, 0.f, 0.f, 0.f};

    // ---- persistent-2 pipeline
    stage_plain(0, oh0a);             // h0(t0)                [only exposed stage]
    LGKM_BARRIER();
    region(0, true, 1, oh0a);         // compute even(t0) || stage h1(t0)
    LGKM_BARRIER();
    region(1, true, 0, oh0b);         // compute odd(t0)  || stage h0(t1)
    epilogue(oh0a);
#pragma unroll
    for (int mt = 0; mt < 4; ++mt)
#pragma unroll
        for (int nt = 0; nt < 4; ++nt)
            acc[mt][nt] = f32x4{0.f, 0.f, 0.f, 0.f};
    LGKM_BARRIER();
    region(0, true, 1, oh0b);         // compute even(t1) || stage h1(t1)
    LGKM_BARRIER();
    region(1, false, 0, 0);           // compute odd(t1)
    epilogue(oh0b);
}

extern "C" void kernel_launch(void* const* d_in, const int* in_sizes, int n_in,
                              void* d_out, int out_size, void* d_ws, size_t ws_size,
                              hipStream_t stream) {
    const float* x    = (const float*)d_in[0];
    const float* lut  = (const float*)d_in[1];
    const int*   widx = (const int*)d_in[2];
    const float* bias = (const float*)d_in[3];
    float* out = (float*)d_out;
    uint4* Bws = (uint4*)d_ws;   // needs 73728 B

    dequant_B<<<18, 256, 0, stream>>>(lut, widx, Bws);
    conv_mfma<<<2048, 256, 0, stream>>>(x, bias, (const uint4*)Bws, out);
}